// Round 1
// baseline (1114.311 us; speedup 1.0000x reference)
//
#include <hip/hip_runtime.h>

// Problem constants (from reference)
#define B_    8
#define CIN_  256
#define H_    128
#define W_    128
#define CC_   16
#define COUT_ 64
// 3x3 ext conv, pad 1; 5x5 corr window, pad 2

// ---------------------------------------------------------------------------
// Kernel A: f[b,c,h,w] = sum_{cin,r,s} x[b,cin,h+r-1,w+s-1] * Wext[c,cin,r,s] + bext[c]
// One thread = one pixel, all 16 output channels.
// Weight loads are wave-uniform -> expect s_load scalarization (SMEM pipe).
// ---------------------------------------------------------------------------
__global__ __launch_bounds__(256) void conv3x3_kernel(
    const float* __restrict__ x, const float* __restrict__ Wext,
    const float* __restrict__ bext, float* __restrict__ f)
{
    const int w = blockIdx.x * 64 + threadIdx.x;   // block (64,4)
    const int h = blockIdx.y * 4 + threadIdx.y;
    const int b = blockIdx.z;

    float acc[CC_];
#pragma unroll
    for (int c = 0; c < CC_; ++c) acc[c] = bext[c];

    const float* xb = x + (size_t)b * CIN_ * H_ * W_;

    for (int cin = 0; cin < CIN_; ++cin) {
        const float* xc = xb + (size_t)cin * H_ * W_;
        float tap[9];
#pragma unroll
        for (int r = 0; r < 3; ++r) {
            const int hh = h + r - 1;
            const bool hv = (hh >= 0) && (hh < H_);
#pragma unroll
            for (int s = 0; s < 3; ++s) {
                const int ww = w + s - 1;
                const bool v = hv && (ww >= 0) && (ww < W_);
                tap[r * 3 + s] = v ? xc[hh * W_ + ww] : 0.0f;
            }
        }
        // Wext[c][cin][t], uniform address per wave
        const float* wp = Wext + cin * 9;
#pragma unroll
        for (int c = 0; c < CC_; ++c) {
#pragma unroll
            for (int t = 0; t < 9; ++t) {
                acc[c] += tap[t] * wp[(size_t)c * CIN_ * 9 + t];
            }
        }
    }

#pragma unroll
    for (int c = 0; c < CC_; ++c) {
        f[(((size_t)b * CC_ + c) * H_ + h) * W_ + w] = acc[c];
    }
}

// ---------------------------------------------------------------------------
// Kernel B: out[b,o,h,w] = sum_{c,k} f[b,c,h,w]*fpad[b,c,h+di,w+dj] * Wreg[o,c,k]
// k = i*5+j, di=i-2, dj=j-2. One thread = one pixel, all 64 outputs.
// ---------------------------------------------------------------------------
__global__ __launch_bounds__(256) void corr_reg_kernel(
    const float* __restrict__ f, const float* __restrict__ Wreg,
    float* __restrict__ out)
{
    const int w = blockIdx.x * 64 + threadIdx.x;   // block (64,4)
    const int h = blockIdx.y * 4 + threadIdx.y;
    const int b = blockIdx.z;

    float acc[COUT_];
#pragma unroll
    for (int o = 0; o < COUT_; ++o) acc[o] = 0.0f;

    for (int c = 0; c < CC_; ++c) {
        const float* fc = f + ((size_t)(b * CC_ + c) * H_) * W_;
        const float center = fc[h * W_ + w];
        float corr[25];
#pragma unroll
        for (int i = 0; i < 5; ++i) {
            const int hh = h + i - 2;
            const bool hv = (hh >= 0) && (hh < H_);
#pragma unroll
            for (int j = 0; j < 5; ++j) {
                const int ww = w + j - 2;
                const bool v = hv && (ww >= 0) && (ww < W_);
                corr[i * 5 + j] = v ? center * fc[hh * W_ + ww] : 0.0f;
            }
        }
        // Wreg[o][c][k], uniform address per wave
        const float* wp = Wreg + (size_t)c * 25;
#pragma unroll 4
        for (int o = 0; o < COUT_; ++o) {
            float s = acc[o];
#pragma unroll
            for (int k = 0; k < 25; ++k) {
                s += corr[k] * wp[(size_t)o * CC_ * 25 + k];
            }
            acc[o] = s;
        }
    }

#pragma unroll
    for (int o = 0; o < COUT_; ++o) {
        out[(((size_t)b * COUT_ + o) * H_ + h) * W_ + w] = acc[o];
    }
}

// ---------------------------------------------------------------------------
extern "C" void kernel_launch(void* const* d_in, const int* in_sizes, int n_in,
                              void* d_out, int out_size, void* d_ws, size_t ws_size,
                              hipStream_t stream) {
    const float* x    = (const float*)d_in[0];  // (8,256,128,128)
    const float* Wext = (const float*)d_in[1];  // (16,256,3,3)
    const float* bext = (const float*)d_in[2];  // (16,)
    const float* Wreg = (const float*)d_in[3];  // (64,16,5,5)
    float* out = (float*)d_out;                 // (8,64,128,128)

    float* f = (float*)d_ws;                    // (8,16,128,128) = 8.4 MB scratch

    dim3 block(64, 4, 1);
    dim3 grid(W_ / 64, H_ / 4, B_);             // (2, 32, 8) = 512 blocks

    conv3x3_kernel<<<grid, block, 0, stream>>>(x, Wext, bext, f);
    corr_reg_kernel<<<grid, block, 0, stream>>>(f, Wreg, out);
}

// Round 2
// 813.009 us; speedup vs baseline: 1.3706x; 1.3706x over previous
//
#include <hip/hip_runtime.h>

#define B_    8
#define CIN_  256
#define H_    128
#define W_    128
#define CC_   16
#define COUT_ 64

// ---------------------------------------------------------------------------
// 16 FMAs fed by 4 float4 weight loads (wave-uniform addresses -> L1 broadcast)
// ---------------------------------------------------------------------------
__device__ __forceinline__ void fma16(float (&acc)[16], float s, const float4* __restrict__ wp) {
    float4 w0 = wp[0], w1 = wp[1], w2 = wp[2], w3 = wp[3];
    acc[0]  += s * w0.x; acc[1]  += s * w0.y; acc[2]  += s * w0.z; acc[3]  += s * w0.w;
    acc[4]  += s * w1.x; acc[5]  += s * w1.y; acc[6]  += s * w1.z; acc[7]  += s * w1.w;
    acc[8]  += s * w2.x; acc[9]  += s * w2.y; acc[10] += s * w2.z; acc[11] += s * w2.w;
    acc[12] += s * w3.x; acc[13] += s * w3.y; acc[14] += s * w3.z; acc[15] += s * w3.w;
}

// ---------------------------------------------------------------------------
// Weight repack: Wext[cc][cin][3][3] -> Wr[cin][tap][cc]   (36864 floats)
//               Wreg[o][cc][5][5]   -> Wr2[cc][k][o]       (25600 floats)
// ---------------------------------------------------------------------------
__global__ void repack_weights(const float* __restrict__ Wext,
                               const float* __restrict__ Wreg,
                               float* __restrict__ Wr, float* __restrict__ Wr2)
{
    int i = blockIdx.x * 256 + threadIdx.x;
    if (i < CIN_ * 9 * CC_) {
        int c = i & 15; int t = (i >> 4) % 9; int cin = i / 144;
        Wr[i] = Wext[c * CIN_ * 9 + cin * 9 + t];
    }
    if (i < CC_ * 25 * COUT_) {
        int o = i & 63; int k = (i >> 6) % 25; int c = i / 1600;
        Wr2[i] = Wreg[o * CC_ * 25 + c * 25 + k];
    }
}

// ---------------------------------------------------------------------------
// Kernel A: f[b,c,h,w] = bias[c] + sum_{cin,tap} x[...] * Wr[cin][tap][c]
// One thread = one pixel, 16 output channels. Tap offsets/masks hoisted.
// ---------------------------------------------------------------------------
__global__ __launch_bounds__(256, 2) void conv3x3_kernel(
    const float* __restrict__ x, const float* __restrict__ Wr,
    const float* __restrict__ bext, float* __restrict__ f)
{
    const int w = blockIdx.x * 64 + (threadIdx.x & 63);
    const int h = blockIdx.y * 4 + (threadIdx.x >> 6);
    const int b = blockIdx.z;

    int  off[9];
    bool valid[9];
#pragma unroll
    for (int r = 0; r < 3; ++r) {
        const int hh = h + r - 1;
        const bool hv = (hh >= 0) && (hh < H_);
#pragma unroll
        for (int s = 0; s < 3; ++s) {
            const int ww = w + s - 1;
            const bool v = hv && (ww >= 0) && (ww < W_);
            off[r * 3 + s]   = v ? hh * W_ + ww : 0;
            valid[r * 3 + s] = v;
        }
    }

    float acc[16];
#pragma unroll
    for (int c = 0; c < 16; ++c) acc[c] = bext[c];

    const float* xb = x + (size_t)b * CIN_ * H_ * W_;
    for (int cin = 0; cin < CIN_; ++cin) {
        const float* xc = xb + (size_t)cin * H_ * W_;
        float tap[9];
#pragma unroll
        for (int t = 0; t < 9; ++t)
            tap[t] = valid[t] ? xc[off[t]] : 0.0f;

        const float4* wp = (const float4*)(Wr + (size_t)cin * 144);
#pragma unroll
        for (int t = 0; t < 9; ++t)
            fma16(acc, tap[t], wp + t * 4);
    }

    const size_t base = ((size_t)b * CC_) * H_ * W_ + h * W_ + w;
#pragma unroll
    for (int c = 0; c < 16; ++c)
        f[base + (size_t)c * H_ * W_] = acc[c];
}

// ---------------------------------------------------------------------------
// Kernel B: out[b,o,h,w] = sum_{c,k} f[b,c,h,w]*f[b,c,h+di,w+dj] * Wr2[c][k][o]
// threadIdx.y = o-group (16 outputs each); 4 threads share a pixel.
// ---------------------------------------------------------------------------
__global__ __launch_bounds__(256, 2) void corr_reg_kernel(
    const float* __restrict__ f, const float* __restrict__ Wr2,
    float* __restrict__ out)
{
    const int w  = blockIdx.x * 64 + threadIdx.x;   // grid.x = 2
    const int h  = blockIdx.y;                      // grid.y = 128
    const int b  = blockIdx.z;
    const int og = threadIdx.y;                     // 0..3 -> o base = og*16

    int  off[25];
    bool valid[25];
#pragma unroll
    for (int i = 0; i < 5; ++i) {
        const int hh = h + i - 2;
        const bool hv = (hh >= 0) && (hh < H_);
#pragma unroll
        for (int j = 0; j < 5; ++j) {
            const int ww = w + j - 2;
            const bool v = hv && (ww >= 0) && (ww < W_);
            off[i * 5 + j]   = v ? hh * W_ + ww : 0;
            valid[i * 5 + j] = v;
        }
    }

    float acc[16];
#pragma unroll
    for (int o = 0; o < 16; ++o) acc[o] = 0.0f;

    const float* fb = f + (size_t)b * CC_ * H_ * W_;
    for (int c = 0; c < CC_; ++c) {
        const float* fc = fb + (size_t)c * H_ * W_;
        const float center = fc[h * W_ + w];
        float corr[25];
#pragma unroll
        for (int k = 0; k < 25; ++k) {
            const float t = valid[k] ? fc[off[k]] : 0.0f;
            corr[k] = center * t;
        }
        // Wr2[c][k][o]: this thread reads o in [og*16, og*16+16)
        const float4* wbase = (const float4*)(Wr2 + (size_t)c * 25 * 64) + og * 4;
#pragma unroll
        for (int k = 0; k < 25; ++k)
            fma16(acc, corr[k], wbase + k * 16);
    }

    const size_t obase = ((size_t)b * COUT_ + og * 16) * H_ * W_ + h * W_ + w;
#pragma unroll
    for (int o = 0; o < 16; ++o)
        out[obase + (size_t)o * H_ * W_] = acc[o];
}

// ---------------------------------------------------------------------------
extern "C" void kernel_launch(void* const* d_in, const int* in_sizes, int n_in,
                              void* d_out, int out_size, void* d_ws, size_t ws_size,
                              hipStream_t stream) {
    const float* x    = (const float*)d_in[0];  // (8,256,128,128)
    const float* Wext = (const float*)d_in[1];  // (16,256,3,3)
    const float* bext = (const float*)d_in[2];  // (16,)
    const float* Wreg = (const float*)d_in[3];  // (64,16,5,5)
    float* out = (float*)d_out;                 // (8,64,128,128)

    float* f   = (float*)d_ws;                               // 2,097,152 floats
    float* Wr  = f + (size_t)B_ * CC_ * H_ * W_;             // 36,864 floats
    float* Wr2 = Wr + (size_t)CIN_ * 9 * CC_;                // 25,600 floats

    repack_weights<<<dim3(144), dim3(256), 0, stream>>>(Wext, Wreg, Wr, Wr2);

    {
        dim3 block(256, 1, 1);
        dim3 grid(W_ / 64, H_ / 4, B_);         // 512 blocks
        conv3x3_kernel<<<grid, block, 0, stream>>>(x, Wr, bext, f);
    }
    {
        dim3 block(64, 4, 1);
        dim3 grid(W_ / 64, H_, B_);             // 2048 blocks
        corr_reg_kernel<<<grid, block, 0, stream>>>(f, Wr2, out);
    }
}

// Round 3
// 752.109 us; speedup vs baseline: 1.4816x; 1.0810x over previous
//
#include <hip/hip_runtime.h>

#define B_    8
#define CIN_  256
#define H_    128
#define W_    128
#define CC_   16
#define COUT_ 64
#define HP_   132            // padded plane dim: rows/cols -2..129
#define PLANE_ (HP_ * HP_)   // 17424 floats per padded plane

// ---------------------------------------------------------------------------
// Weight repack: Wext[cc][cin][3][3] -> Wr[cin][tap][cc]   (36864 floats)
//               Wreg[o][cc][5][5]   -> Wr2[cc][k][o]       (25600 floats)
// ---------------------------------------------------------------------------
__global__ void repack_weights(const float* __restrict__ Wext,
                               const float* __restrict__ Wreg,
                               float* __restrict__ Wr, float* __restrict__ Wr2)
{
    int i = blockIdx.x * 256 + threadIdx.x;
    if (i < CIN_ * 9 * CC_) {
        int c = i & 15; int t = (i >> 4) % 9; int cin = i / 144;
        Wr[i] = Wext[c * CIN_ * 9 + cin * 9 + t];
    }
    if (i < CC_ * 25 * COUT_) {
        int o = i & 63; int k = (i >> 6) % 25; int c = i / 1600;
        Wr2[i] = Wreg[o * CC_ * 25 + c * 25 + k];
    }
}

// ---------------------------------------------------------------------------
// Kernel A: conv3x3. Thread = (w, cc-group of 4, 2 rows h0/h0+1).
// Writes into zero-padded fpad at (h+2, w+2).
// ---------------------------------------------------------------------------
__global__ __launch_bounds__(256, 4) void conv3x3_kernel(
    const float* __restrict__ x, const float4* __restrict__ Wr4,
    const float* __restrict__ bext, float* __restrict__ fpad)
{
    const int w  = blockIdx.x * 64 + threadIdx.x;   // grid.x = 2
    const int cg = threadIdx.y;                     // 4 cc per group
    const int h0 = blockIdx.y * 2;                  // grid.y = 64
    const int b  = blockIdx.z;

    // validity masks (computed once)
    const bool vwl = (w > 0), vwr = (w < W_ - 1);
    bool vr[4];
    int  roff[4];   // clamped row offsets (safe addresses, select-after-load)
#pragma unroll
    for (int rr = 0; rr < 4; ++rr) {
        const int hh = h0 - 1 + rr;
        vr[rr]   = (hh >= 0) && (hh < H_);
        roff[rr] = (vr[rr] ? hh : 0) * W_;
    }

    const float4 bv = ((const float4*)bext)[cg];
    float acc0[4] = {bv.x, bv.y, bv.z, bv.w};   // pixel (h0,   w)
    float acc1[4] = {bv.x, bv.y, bv.z, bv.w};   // pixel (h0+1, w)

    const float* xb = x + (size_t)b * CIN_ * H_ * W_;
    for (int cin = 0; cin < CIN_; ++cin) {
        const float* xc = xb + (size_t)cin * (H_ * W_);
        float xv[4][3];
#pragma unroll
        for (int rr = 0; rr < 4; ++rr) {
            const float* rp = xc + roff[rr] + w;
            const float a = rp[vwl ? -1 : 0];
            const float m = rp[0];
            const float z = rp[vwr ? 1 : 0];
            xv[rr][0] = (vr[rr] && vwl) ? a : 0.0f;
            xv[rr][1] = vr[rr] ? m : 0.0f;
            xv[rr][2] = (vr[rr] && vwr) ? z : 0.0f;
        }
        const float4* wp = Wr4 + (size_t)cin * 36 + cg;
#pragma unroll
        for (int r = 0; r < 3; ++r) {
#pragma unroll
            for (int s = 0; s < 3; ++s) {
                const float4 wq = wp[(r * 3 + s) * 4];
                const float t0 = xv[r][s];       // row h0-1+r  -> pixel h0
                const float t1 = xv[r + 1][s];   // row h0+r    -> pixel h0+1
                acc0[0] += t0 * wq.x; acc1[0] += t1 * wq.x;
                acc0[1] += t0 * wq.y; acc1[1] += t1 * wq.y;
                acc0[2] += t0 * wq.z; acc1[2] += t1 * wq.z;
                acc0[3] += t0 * wq.w; acc1[3] += t1 * wq.w;
            }
        }
    }

    float* fp = fpad + (size_t)(b * CC_ + cg * 4) * PLANE_ + (h0 + 2) * HP_ + (w + 2);
#pragma unroll
    for (int c = 0; c < 4; ++c) {
        fp[(size_t)c * PLANE_]       = acc0[c];
        fp[(size_t)c * PLANE_ + HP_] = acc1[c];
    }
}

// ---------------------------------------------------------------------------
// 32 FMAs (16 outputs x 2 pixels) fed by 4 float4 weight loads
// ---------------------------------------------------------------------------
__device__ __forceinline__ void fma16x2(float (&a0)[16], float (&a1)[16],
                                        float p0, float p1,
                                        const float4* __restrict__ wq) {
    const float4 w0 = wq[0], w1 = wq[1], w2 = wq[2], w3 = wq[3];
    a0[0]  += p0 * w0.x; a1[0]  += p1 * w0.x;
    a0[1]  += p0 * w0.y; a1[1]  += p1 * w0.y;
    a0[2]  += p0 * w0.z; a1[2]  += p1 * w0.z;
    a0[3]  += p0 * w0.w; a1[3]  += p1 * w0.w;
    a0[4]  += p0 * w1.x; a1[4]  += p1 * w1.x;
    a0[5]  += p0 * w1.y; a1[5]  += p1 * w1.y;
    a0[6]  += p0 * w1.z; a1[6]  += p1 * w1.z;
    a0[7]  += p0 * w1.w; a1[7]  += p1 * w1.w;
    a0[8]  += p0 * w2.x; a1[8]  += p1 * w2.x;
    a0[9]  += p0 * w2.y; a1[9]  += p1 * w2.y;
    a0[10] += p0 * w2.z; a1[10] += p1 * w2.z;
    a0[11] += p0 * w2.w; a1[11] += p1 * w2.w;
    a0[12] += p0 * w3.x; a1[12] += p1 * w3.x;
    a0[13] += p0 * w3.y; a1[13] += p1 * w3.y;
    a0[14] += p0 * w3.z; a1[14] += p1 * w3.z;
    a0[15] += p0 * w3.w; a1[15] += p1 * w3.w;
}

// ---------------------------------------------------------------------------
// Kernel B: corr + regressor. Thread = (w, o-group of 16, 2 rows h0/h0+1).
// Reads zero-padded fpad -> no masks in the inner loop.
// ---------------------------------------------------------------------------
__global__ __launch_bounds__(256, 4) void corr_reg_kernel(
    const float* __restrict__ fpad, const float4* __restrict__ Wr2_4,
    float* __restrict__ out)
{
    const int w  = blockIdx.x * 64 + threadIdx.x;   // grid.x = 2
    const int og = threadIdx.y;                     // o = og*16 .. og*16+15
    const int h0 = blockIdx.y * 2;                  // grid.y = 64
    const int b  = blockIdx.z;

    float acc0[16], acc1[16];
#pragma unroll
    for (int o = 0; o < 16; ++o) { acc0[o] = 0.0f; acc1[o] = 0.0f; }

    const float* fb = fpad + (size_t)b * CC_ * PLANE_;
    for (int c = 0; c < CC_; ++c) {
        const float* fc = fb + (size_t)c * PLANE_;
        // window: padded rows h0..h0+5 (actual h0-2..h0+3), padded cols w..w+4
        float fw[6][5];
#pragma unroll
        for (int rr = 0; rr < 6; ++rr) {
            const float* rp = fc + (size_t)(h0 + rr) * HP_ + w;
#pragma unroll
            for (int cc = 0; cc < 5; ++cc)
                fw[rr][cc] = rp[cc];
        }
        const float c0 = fw[2][2];   // f at (h0,   w)
        const float c1 = fw[3][2];   // f at (h0+1, w)

        // Wr2 float idx (c*25+k)*64 + o  -> float4 idx (c*25+k)*16 + og*4 + q
        const float4* wp = Wr2_4 + (size_t)c * 400 + og * 4;
#pragma unroll
        for (int i = 0; i < 5; ++i) {
#pragma unroll
            for (int j = 0; j < 5; ++j) {
                const int k = i * 5 + j;
                const float p0 = c0 * fw[i][j];       // shift (i-2, j-2) for pixel h0
                const float p1 = c1 * fw[i + 1][j];   // same shift for pixel h0+1
                fma16x2(acc0, acc1, p0, p1, wp + k * 16);
            }
        }
    }

    const size_t ob = ((size_t)b * COUT_ + og * 16) * (H_ * W_) + (size_t)h0 * W_ + w;
#pragma unroll
    for (int o = 0; o < 16; ++o) {
        out[ob + (size_t)o * H_ * W_]      = acc0[o];
        out[ob + (size_t)o * H_ * W_ + W_] = acc1[o];
    }
}

// ---------------------------------------------------------------------------
extern "C" void kernel_launch(void* const* d_in, const int* in_sizes, int n_in,
                              void* d_out, int out_size, void* d_ws, size_t ws_size,
                              hipStream_t stream) {
    const float* x    = (const float*)d_in[0];  // (8,256,128,128)
    const float* Wext = (const float*)d_in[1];  // (16,256,3,3)
    const float* bext = (const float*)d_in[2];  // (16,)
    const float* Wreg = (const float*)d_in[3];  // (64,16,5,5)
    float* out = (float*)d_out;                 // (8,64,128,128)

    float* fpad = (float*)d_ws;                              // 2,230,272 floats (~8.9 MB)
    float* Wr   = fpad + (size_t)B_ * CC_ * PLANE_;          // 36,864 floats
    float* Wr2  = Wr + (size_t)CIN_ * 9 * CC_;               // 25,600 floats

    // zero the padded f buffer (ws is re-poisoned to 0xAA before every launch)
    hipMemsetAsync(fpad, 0, (size_t)B_ * CC_ * PLANE_ * sizeof(float), stream);

    repack_weights<<<dim3(144), dim3(256), 0, stream>>>(Wext, Wreg, Wr, Wr2);

    {
        dim3 block(64, 4, 1);
        dim3 grid(W_ / 64, H_ / 2, B_);         // (2, 64, 8) = 1024 blocks
        conv3x3_kernel<<<grid, block, 0, stream>>>(x, (const float4*)Wr, bext, fpad);
    }
    {
        dim3 block(64, 4, 1);
        dim3 grid(W_ / 64, H_ / 2, B_);         // (2, 64, 8) = 1024 blocks
        corr_reg_kernel<<<grid, block, 0, stream>>>(fpad, (const float4*)Wr2, out);
    }
}

// Round 4
// 400.702 us; speedup vs baseline: 2.7809x; 1.8770x over previous
//
#include <hip/hip_runtime.h>

#define B_    8
#define CIN_  256
#define H_    128
#define W_    128
#define CC_   16
#define COUT_ 64
#define HXT_  130           // xt padded dim (pad 1)
#define HFP_  132           // fpad padded dim (pad 2)

typedef _Float16 half8 __attribute__((ext_vector_type(8)));
typedef _Float16 half2v __attribute__((ext_vector_type(2)));
typedef float float4v __attribute__((ext_vector_type(4)));

// ---------------------------------------------------------------------------
// Repack Wext[cc][cin][3][3] -> Wa1[tap][cinblk][lane][j] (f16 A-fragments)
//   value = Wext[cc = lane&15][cin = cinblk*32 + (lane>>4)*8 + j][tap]
// ---------------------------------------------------------------------------
__global__ void repack_w1(const float* __restrict__ Wext, _Float16* __restrict__ Wa1) {
    int i = blockIdx.x * 256 + threadIdx.x;          // 36864 total
    if (i >= 9 * 8 * 64 * 8) return;
    int j    = i & 7;
    int lane = (i >> 3) & 63;
    int blk  = (i >> 9) & 7;
    int tap  = i >> 12;
    int cc   = lane & 15;
    int cin  = blk * 32 + (lane >> 4) * 8 + j;
    Wa1[i] = (_Float16)Wext[cc * (CIN_ * 9) + cin * 9 + tap];
}

// ---------------------------------------------------------------------------
// Repack Wreg[o][c][kk] -> Wa2[ogrp][s][lane][j] (f16 A-fragments), K padded 400->416
//   q=lane>>4; kk=2s+(q>>1); c=(q&1)*8+j; o=ogrp*16+(lane&15); zero if kk>=25
// ---------------------------------------------------------------------------
__global__ void repack_w2(const float* __restrict__ Wreg, _Float16* __restrict__ Wa2) {
    int u = blockIdx.x * 256 + threadIdx.x;          // 26624 total
    if (u >= 4 * 13 * 64 * 8) return;
    int j    = u & 7;
    int lane = (u >> 3) & 63;
    int su   = u >> 9;                               // g*13 + s
    int s    = su % 13;
    int g    = su / 13;
    int q    = lane >> 4;
    int kk   = 2 * s + (q >> 1);
    int c    = (q & 1) * 8 + j;
    int o    = g * 16 + (lane & 15);
    float v  = (kk < 25) ? Wreg[o * (CC_ * 25) + c * 25 + kk] : 0.0f;
    Wa2[u] = (_Float16)v;
}

// ---------------------------------------------------------------------------
// Zero the 1-px border of xt (516 border pixels per image, 512 B each)
// ---------------------------------------------------------------------------
__global__ void zero_xt_border(_Float16* __restrict__ xt) {
    int t = blockIdx.x * 256 + threadIdx.x;
    int b = blockIdx.z;
    if (t >= 516 * 32) return;
    int px = t >> 5, ch = t & 31;
    int hp, wp;
    if (px < 130)      { hp = 0;            wp = px; }
    else if (px < 260) { hp = 129;          wp = px - 130; }
    else if (px < 388) { hp = px - 260 + 1; wp = 0; }
    else               { hp = px - 388 + 1; wp = 129; }
    size_t idx = (((size_t)b * HXT_ + hp) * HXT_ + wp) * 256 + ch * 8;
    half8 z = {};
    *(half8*)(xt + idx) = z;
}

// ---------------------------------------------------------------------------
// Transpose+convert: x[b][cin][h][w] fp32 -> xt[b][h+1][w+1][cin] f16
// Coalesced reads (lanes along w); ushort2 writes (cin-pairs).
// ---------------------------------------------------------------------------
__global__ __launch_bounds__(256) void transpose_x(const float* __restrict__ x,
                                                   _Float16* __restrict__ xt) {
    const int tx = threadIdx.x;          // 0..63 = w
    const int ty = threadIdx.y;          // 0..3
    const int w  = blockIdx.x * 64 + tx;
    const int h  = blockIdx.y;
    const int b  = blockIdx.z;

    const float* xb = x + ((size_t)b * CIN_) * (H_ * W_) + h * W_ + w;
    _Float16* dst = xt + (((size_t)b * HXT_ + h + 1) * HXT_ + (w + 1)) * 256;

#pragma unroll 4
    for (int it = 0; it < 32; ++it) {
        int c2 = it * 8 + ty * 2;
        float a = xb[(size_t)c2 * (H_ * W_)];
        float c = xb[(size_t)(c2 + 1) * (H_ * W_)];
        half2v p;
        p[0] = (_Float16)a;
        p[1] = (_Float16)c;
        *(half2v*)(dst + c2) = p;
    }
}

// ---------------------------------------------------------------------------
// Stage 1: conv3x3 via MFMA. Wave = 64 px (4 strips of 16) x 16 cc, one h row.
// A = weight frag (M=cc), B = x frag (N=px), K = 9 taps x 256 cin.
// Output -> fpad f16 via LDS transpose (cc-contiguous rows).
// ---------------------------------------------------------------------------
__global__ __launch_bounds__(256, 4) void conv_mfma(
    const _Float16* __restrict__ xt, const _Float16* __restrict__ Wa1,
    const float* __restrict__ bext, _Float16* __restrict__ fpad)
{
    __shared__ _Float16 lds[4][64][16];

    const int lane = threadIdx.x;            // 0..63
    const int wv   = threadIdx.y;            // 0..3
    const int n    = lane & 15;
    const int q    = lane >> 4;
    const int h    = blockIdx.y * 4 + wv;
    const int w0   = blockIdx.x * 64;
    const int b    = blockIdx.z;

    float4v acc[4] = {};   // 4 strips x (4 fp32/lane)

    // base: xt[b][h + r][w0 + strip*16 + n + s][cinblk*32 + q*8]
    const _Float16* xbase = xt + (((size_t)b * HXT_ + h) * HXT_ + (w0 + n)) * 256 + q * 8;

#pragma unroll
    for (int r = 0; r < 3; ++r) {
#pragma unroll
        for (int s = 0; s < 3; ++s) {
            const _Float16* xrs = xbase + (r * HXT_ + s) * 256;
            const _Float16* wrs = Wa1 + (size_t)(r * 3 + s) * 4096 + lane * 8;
#pragma unroll
            for (int blk = 0; blk < 8; ++blk) {
                half8 af = *(const half8*)(wrs + blk * 512);
#pragma unroll
                for (int st = 0; st < 4; ++st) {
                    half8 bf = *(const half8*)(xrs + st * 16 * 256 + blk * 32);
                    acc[st] = __builtin_amdgcn_mfma_f32_16x16x32_f16(af, bf, acc[st], 0, 0, 0);
                }
            }
        }
    }

    // epilogue: bias + f32->f16, LDS transpose to cc-contiguous, write fpad
    float bias[4];
#pragma unroll
    for (int rr = 0; rr < 4; ++rr) bias[rr] = bext[q * 4 + rr];

#pragma unroll
    for (int st = 0; st < 4; ++st) {
#pragma unroll
        for (int rr = 0; rr < 4; ++rr) {
            lds[wv][st * 16 + n][q * 4 + rr] = (_Float16)(acc[st][rr] + bias[rr]);
        }
    }
    __syncthreads();

    half8 o0 = *(const half8*)&lds[wv][lane][0];
    half8 o1 = *(const half8*)&lds[wv][lane][8];
    _Float16* dst = fpad + (((size_t)b * HFP_ + (h + 2)) * HFP_ + (w0 + lane + 2)) * 16;
    *(half8*)dst = o0;
    *(half8*)(dst + 8) = o1;
}

// ---------------------------------------------------------------------------
// Stage 2: corr + regressor via MFMA. Wave = 16 px x 64 o, one h row.
// A = Wreg frag (M=o), B = corr frag (N=px) built with pk_mul from fpad.
// K = 25 kk x 16 c (padded to 416): step s covers kk = 2s + (q>>1).
// ---------------------------------------------------------------------------
__global__ __launch_bounds__(256, 4) void corr_mfma(
    const _Float16* __restrict__ fpad, const _Float16* __restrict__ Wa2,
    float* __restrict__ out)
{
    const int lane = threadIdx.x;
    const int wv   = threadIdx.y;
    const int n    = lane & 15;
    const int q    = lane >> 4;
    const int h    = blockIdx.y;
    const int w0   = blockIdx.x * 64 + wv * 16;
    const int b    = blockIdx.z;

    const _Float16* fb = fpad + ((size_t)b * HFP_ + h) * (HFP_ * 16);
    const int coff = (q & 1) * 8;

    // center: f[px][c-half], reused for all steps
    half8 ctr = *(const half8*)(fb + (size_t)(2 * HFP_ + (w0 + n + 2)) * 16 + coff);

    float4v acc[4] = {};

#pragma unroll
    for (int s = 0; s < 13; ++s) {
        int kk = 2 * s + (q >> 1);
        if (kk > 24) kk = 24;                 // s=12,q>=2: weights are zero
        const int ki = kk / 5, kj = kk % 5;
        half8 sh = *(const half8*)(fb + (size_t)(ki * HFP_ + (w0 + n + kj)) * 16 + coff);
        half8 corr = ctr * sh;                // 4x v_pk_mul_f16
#pragma unroll
        for (int g = 0; g < 4; ++g) {
            half8 wf = *(const half8*)(Wa2 + ((size_t)(g * 13 + s) * 64 + lane) * 8);
            acc[g] = __builtin_amdgcn_mfma_f32_16x16x32_f16(wf, corr, acc[g], 0, 0, 0);
        }
    }

    // D: row = o-in-group = q*4+reg, col = px = n
#pragma unroll
    for (int g = 0; g < 4; ++g) {
#pragma unroll
        for (int rr = 0; rr < 4; ++rr) {
            int o = g * 16 + q * 4 + rr;
            out[((size_t)(b * COUT_ + o) * H_ + h) * W_ + (w0 + n)] = acc[g][rr];
        }
    }
}

// ---------------------------------------------------------------------------
extern "C" void kernel_launch(void* const* d_in, const int* in_sizes, int n_in,
                              void* d_out, int out_size, void* d_ws, size_t ws_size,
                              hipStream_t stream) {
    const float* x    = (const float*)d_in[0];  // (8,256,128,128)
    const float* Wext = (const float*)d_in[1];  // (16,256,3,3)
    const float* bext = (const float*)d_in[2];  // (16,)
    const float* Wreg = (const float*)d_in[3];  // (64,16,5,5)
    float* out = (float*)d_out;                 // (8,64,128,128)

    char* ws = (char*)d_ws;
    _Float16* xt   = (_Float16*)ws;                       // 8*130*130*256 f16 = 69,222,400 B
    _Float16* fpad = (_Float16*)(ws + 69222400);          // 8*132*132*16 f16 =  4,460,544 B
    _Float16* Wa1  = (_Float16*)(ws + 69222400 + 4460544);            // 73,728 B
    _Float16* Wa2  = (_Float16*)(ws + 69222400 + 4460544 + 73728);    // 53,248 B

    repack_w1<<<dim3(144), dim3(256), 0, stream>>>(Wext, Wa1);
    repack_w2<<<dim3(104), dim3(256), 0, stream>>>(Wreg, Wa2);
    zero_xt_border<<<dim3(65, 1, 8), dim3(256), 0, stream>>>(xt);
    hipMemsetAsync(fpad, 0, (size_t)B_ * CC_ * HFP_ * HFP_ * sizeof(_Float16), stream);

    transpose_x<<<dim3(2, 128, 8), dim3(64, 4), 0, stream>>>(x, xt);
    conv_mfma<<<dim3(2, 32, 8), dim3(64, 4), 0, stream>>>(xt, Wa1, bext, fpad);
    corr_mfma<<<dim3(2, 128, 8), dim3(64, 4), 0, stream>>>(fpad, Wa2, out);
}

// Round 5
// 274.169 us; speedup vs baseline: 4.0643x; 1.4615x over previous
//
#include <hip/hip_runtime.h>

#define B_    8
#define CIN_  256
#define H_    128
#define W_    128
#define CC_   16
#define COUT_ 64
#define HFP_  132            // fpad padded dim (pad 2)

typedef _Float16 half8 __attribute__((ext_vector_type(8)));
typedef float float4v __attribute__((ext_vector_type(4)));

// ---------------------------------------------------------------------------
// Repack Wext[cc][cin][3][3] -> Wa1[tap][cinblk][lane][j] (f16 A-fragments)
//   value = Wext[cc = lane&15][cin = cinblk*32 + (lane>>4)*8 + j][tap]
// ---------------------------------------------------------------------------
__global__ void repack_w1(const float* __restrict__ Wext, _Float16* __restrict__ Wa1) {
    int i = blockIdx.x * 256 + threadIdx.x;          // 36864 total
    if (i >= 9 * 8 * 64 * 8) return;
    int j    = i & 7;
    int lane = (i >> 3) & 63;
    int blk  = (i >> 9) & 7;
    int tap  = i >> 12;
    int cc   = lane & 15;
    int cin  = blk * 32 + (lane >> 4) * 8 + j;
    Wa1[i] = (_Float16)Wext[cc * (CIN_ * 9) + cin * 9 + tap];
}

// ---------------------------------------------------------------------------
// Repack Wreg[o][c][kk] -> Wa2[ogrp][s][lane][j] (f16 A-fragments), K padded 400->416
// ---------------------------------------------------------------------------
__global__ void repack_w2(const float* __restrict__ Wreg, _Float16* __restrict__ Wa2) {
    int u = blockIdx.x * 256 + threadIdx.x;          // 26624 total
    if (u >= 4 * 13 * 64 * 8) return;
    int j    = u & 7;
    int lane = (u >> 3) & 63;
    int su   = u >> 9;                               // g*13 + s
    int s    = su % 13;
    int g    = su / 13;
    int q    = lane >> 4;
    int kk   = 2 * s + (q >> 1);
    int c    = (q & 1) * 8 + j;
    int o    = g * 16 + (lane & 15);
    float v  = (kk < 25) ? Wreg[o * (CC_ * 25) + c * 25 + kk] : 0.0f;
    Wa2[u] = (_Float16)v;
}

// ---------------------------------------------------------------------------
// Fused Stage 1: conv3x3 via MFMA with in-kernel LDS staging of x (no xt).
// Block = 64 px x 4 rows. K-loop: 8 chunks of 32 cin.
// LDS xs layout: [c8][row][col][8] f16, c8-stride 3170 f16 (17 dwords mod 32
// -> conflict-free b128 fragment reads: bank = 4*(col) + 17*q, 2 lanes/bank).
// ---------------------------------------------------------------------------
__global__ __launch_bounds__(256, 2) void conv_fused(
    const float* __restrict__ x, const _Float16* __restrict__ Wa1,
    const float* __restrict__ bext, _Float16* __restrict__ fpad)
{
    __shared__ _Float16 xs[4 * 3170];        // 25,360 B staging
    __shared__ _Float16 lt[4][64][16];       // 8,192 B epilogue transpose

    const int lane = threadIdx.x;            // 0..63
    const int wv   = threadIdx.y;            // 0..3
    const int tid  = wv * 64 + lane;
    const int n    = lane & 15;
    const int q    = lane >> 4;
    const int h0   = blockIdx.y * 4;
    const int w0   = blockIdx.x * 64;
    const int b    = blockIdx.z;

    // ---- precompute staging descriptors: units u = p*256+tid over
    //      (c8 in 0..3) x (row in 0..5) x (col in 0..65), 1584 units ----
    int  goff[7];     // fp32 element offset within this image, chunk 0
    int  loff[7];     // f16 index into xs
    bool vld[7];
#pragma unroll
    for (int p = 0; p < 7; ++p) {
        int u = p * 256 + tid;
        if (u > 1583) u = 0;                 // guarded at use
        const int col  = u % 66;
        const int pair = u / 66;             // 0..23
        const int row  = pair % 6;
        const int c8   = pair / 6;           // 0..3
        const int hh = h0 - 1 + row;
        const int ww = w0 - 1 + col;
        vld[p] = (hh >= 0) && (hh < H_) && (ww >= 0) && (ww < W_);
        const int hc = hh < 0 ? 0 : (hh > H_ - 1 ? H_ - 1 : hh);
        const int wc = ww < 0 ? 0 : (ww > W_ - 1 ? W_ - 1 : ww);
        goff[p] = (c8 * 8) * (H_ * W_) + hc * W_ + wc;
        loff[p] = c8 * 3170 + (row * 66 + col) * 8;
    }

    const float* xb = x + (size_t)b * (CIN_ * H_ * W_);
    float4v acc[4] = {};

    for (int chunk = 0; chunk < 8; ++chunk) {
        __syncthreads();                     // protect xs from previous reads
        const float* xc = xb + (size_t)chunk * (32 * H_ * W_);
#pragma unroll
        for (int p = 0; p < 7; ++p) {
            if (p != 6 || tid < 48) {
                half8 hv;
#pragma unroll
                for (int j = 0; j < 8; ++j) {
                    const float v = xc[goff[p] + j * (H_ * W_)];
                    hv[j] = (_Float16)(vld[p] ? v : 0.0f);
                }
                *(half8*)(xs + loff[p]) = hv;
            }
        }
        __syncthreads();

        const _Float16* wchunk = Wa1 + (size_t)chunk * 512 + lane * 8;
        const _Float16* xsb    = xs + q * 3170 + (wv * 66 + n) * 8;
#pragma unroll
        for (int r = 0; r < 3; ++r) {
#pragma unroll
            for (int s = 0; s < 3; ++s) {
                const half8 af = *(const half8*)(wchunk + (r * 3 + s) * 4096);
#pragma unroll
                for (int st = 0; st < 4; ++st) {
                    const half8 bf = *(const half8*)(xsb + (r * 66 + s + st * 16) * 8);
                    acc[st] = __builtin_amdgcn_mfma_f32_16x16x32_f16(af, bf, acc[st], 0, 0, 0);
                }
            }
        }
    }

    // epilogue: bias + f32->f16, per-wave LDS transpose, write fpad (cc-contig)
    float bias[4];
#pragma unroll
    for (int rr = 0; rr < 4; ++rr) bias[rr] = bext[q * 4 + rr];

#pragma unroll
    for (int st = 0; st < 4; ++st) {
#pragma unroll
        for (int rr = 0; rr < 4; ++rr) {
            lt[wv][st * 16 + n][q * 4 + rr] = (_Float16)(acc[st][rr] + bias[rr]);
        }
    }
    __syncthreads();

    const half8 o0 = *(const half8*)&lt[wv][lane][0];
    const half8 o1 = *(const half8*)&lt[wv][lane][8];
    _Float16* dst = fpad + (((size_t)b * HFP_ + (h0 + wv + 2)) * HFP_ + (w0 + lane + 2)) * 16;
    *(half8*)dst = o0;
    *(half8*)(dst + 8) = o1;
}

// ---------------------------------------------------------------------------
// Stage 2: corr + regressor via MFMA (unchanged from round 4).
// ---------------------------------------------------------------------------
__global__ __launch_bounds__(256, 4) void corr_mfma(
    const _Float16* __restrict__ fpad, const _Float16* __restrict__ Wa2,
    float* __restrict__ out)
{
    const int lane = threadIdx.x;
    const int wv   = threadIdx.y;
    const int n    = lane & 15;
    const int q    = lane >> 4;
    const int h    = blockIdx.y;
    const int w0   = blockIdx.x * 64 + wv * 16;
    const int b    = blockIdx.z;

    const _Float16* fb = fpad + ((size_t)b * HFP_ + h) * (HFP_ * 16);
    const int coff = (q & 1) * 8;

    const half8 ctr = *(const half8*)(fb + (size_t)(2 * HFP_ + (w0 + n + 2)) * 16 + coff);

    float4v acc[4] = {};

#pragma unroll
    for (int s = 0; s < 13; ++s) {
        int kk = 2 * s + (q >> 1);
        if (kk > 24) kk = 24;                 // s=12,q>=2: weights are zero
        const int ki = kk / 5, kj = kk % 5;
        const half8 sh = *(const half8*)(fb + (size_t)(ki * HFP_ + (w0 + n + kj)) * 16 + coff);
        const half8 corr = ctr * sh;          // 4x v_pk_mul_f16
#pragma unroll
        for (int g = 0; g < 4; ++g) {
            const half8 wf = *(const half8*)(Wa2 + ((size_t)(g * 13 + s) * 64 + lane) * 8);
            acc[g] = __builtin_amdgcn_mfma_f32_16x16x32_f16(wf, corr, acc[g], 0, 0, 0);
        }
    }

#pragma unroll
    for (int g = 0; g < 4; ++g) {
#pragma unroll
        for (int rr = 0; rr < 4; ++rr) {
            const int o = g * 16 + q * 4 + rr;
            out[((size_t)(b * COUT_ + o) * H_ + h) * W_ + (w0 + n)] = acc[g][rr];
        }
    }
}

// ---------------------------------------------------------------------------
extern "C" void kernel_launch(void* const* d_in, const int* in_sizes, int n_in,
                              void* d_out, int out_size, void* d_ws, size_t ws_size,
                              hipStream_t stream) {
    const float* x    = (const float*)d_in[0];  // (8,256,128,128)
    const float* Wext = (const float*)d_in[1];  // (16,256,3,3)
    const float* bext = (const float*)d_in[2];  // (16,)
    const float* Wreg = (const float*)d_in[3];  // (64,16,5,5)
    float* out = (float*)d_out;                 // (8,64,128,128)

    char* ws = (char*)d_ws;
    _Float16* fpad = (_Float16*)ws;                       // 8*132*132*16 f16 = 4,460,544 B
    _Float16* Wa1  = (_Float16*)(ws + 4460544);           // 73,728 B
    _Float16* Wa2  = (_Float16*)(ws + 4460544 + 73728);   // 53,248 B

    repack_w1<<<dim3(144), dim3(256), 0, stream>>>(Wext, Wa1);
    repack_w2<<<dim3(104), dim3(256), 0, stream>>>(Wreg, Wa2);
    hipMemsetAsync(fpad, 0, (size_t)B_ * CC_ * HFP_ * HFP_ * sizeof(_Float16), stream);

    conv_fused<<<dim3(2, 32, 8), dim3(64, 4), 0, stream>>>(x, Wa1, bext, fpad);
    corr_mfma<<<dim3(2, 128, 8), dim3(64, 4), 0, stream>>>(fpad, Wa2, out);
}